// Round 1
// 744.203 us; speedup vs baseline: 1.0425x; 1.0425x over previous
//
#include <hip/hip_runtime.h>

// Problem constants (fixed by the reference):
//   B=4096 tokens, K=8 experts/token, H=4096 hidden, E=64 experts, N=B*K=32768
#define B_TOK 4096
#define K_EXP 8
#define H_DIM 4096
#define E_NUM 64
#define N_SLOT (B_TOK * K_EXP)       // 32768

typedef float vf4 __attribute__((ext_vector_type(4)));

// ---------------------------------------------------------------------------
// Single fused kernel. One block per token (4096 blocks x 256 threads).
//
// Phase 1 — rank: the stable-sort position of slot i is
//     inv[i] = #{ j : key(j) < key(i) },  key(j) = (e_j << 15) | j
// (e < 64 -> 6 bits, j < 32768 -> 15 bits, key < 2^21; strict stable order).
// Each block scans all 32768 expert ids (128 KB, coalesced int4 -> L2-hit
// after the first wave of blocks) and counts via ballot+popcount: one v_cmp
// per 64 elements per target, accumulate on the scalar pipe. ~17 us of
// chip-wide VALU, hidden under the combine memory phase.
//
// Phase 2 — combine: out[b,h] = sum_k s[b,k] * ex[inv[b*K+k], h], written to
// both output copies. ex rows are each read exactly once across the grid ->
// nontemporal loads (don't thrash L2, which holds the 128 KB eids array);
// nontemporal stores for the outputs.
//
// No workspace, no inter-kernel dependencies, one launch.
// ---------------------------------------------------------------------------
__global__ __launch_bounds__(256) void moe_fused(
        const int*   __restrict__ eids,
        const float* __restrict__ scales,
        const float* __restrict__ ex,
        float* __restrict__ out0,
        float* __restrict__ out1) {
    const int b    = blockIdx.x;
    const int tid  = threadIdx.x;
    const int lane = tid & 63;
    const int wid  = tid >> 6;

    // ---- Phase 1: global stable rank of this token's 8 slots ----
    unsigned kk[K_EXP];
#pragma unroll
    for (int k = 0; k < K_EXP; ++k) {
        const int i = b * K_EXP + k;
        kk[k] = ((unsigned)eids[i] << 15) | (unsigned)i;   // uniform broadcast load
    }

    int cnt[K_EXP];
#pragma unroll
    for (int k = 0; k < K_EXP; ++k) cnt[k] = 0;

    const int4* e4 = (const int4*)eids;       // 8192 int4 total
    for (int s = 0; s < N_SLOT / 4 / 256; ++s) {   // 32 steps
        const int idx = s * 256 + tid;        // coalesced: 1 KB per wave
        const int4 v  = e4[idx];
        const unsigned j0 = (unsigned)idx * 4u;
        const unsigned kj0 = ((unsigned)v.x << 15) | (j0 + 0u);
        const unsigned kj1 = ((unsigned)v.y << 15) | (j0 + 1u);
        const unsigned kj2 = ((unsigned)v.z << 15) | (j0 + 2u);
        const unsigned kj3 = ((unsigned)v.w << 15) | (j0 + 3u);
#pragma unroll
        for (int k = 0; k < K_EXP; ++k) {
            cnt[k] += __popcll(__ballot(kj0 < kk[k]));
            cnt[k] += __popcll(__ballot(kj1 < kk[k]));
            cnt[k] += __popcll(__ballot(kj2 < kk[k]));
            cnt[k] += __popcll(__ballot(kj3 < kk[k]));
        }
    }
    // cnt[k] is wave-uniform (ballot counts the whole wave's elements);
    // reduce across the 4 waves of the block.
    __shared__ int   red[4][K_EXP];
    __shared__ int   rows[K_EXP];
    __shared__ float ss[K_EXP];
    if (lane == 0) {
#pragma unroll
        for (int k = 0; k < K_EXP; ++k) red[wid][k] = cnt[k];
    }
    __syncthreads();
    if (tid < K_EXP) {
        rows[tid] = red[0][tid] + red[1][tid] + red[2][tid] + red[3][tid];
        ss[tid]   = scales[b * K_EXP + tid];
    }
    __syncthreads();

    // ---- Phase 2: combine ----
    const vf4* ex4 = (const vf4*)ex;
    vf4* o0 = (vf4*)(out0 + (size_t)b * H_DIM);
    vf4* o1 = (vf4*)(out1 + (size_t)b * H_DIM);
    const int H4 = H_DIM / 4;                 // 1024 vf4 per row

    size_t rbase[K_EXP];
    float  sreg[K_EXP];
#pragma unroll
    for (int k = 0; k < K_EXP; ++k) {
        rbase[k] = (size_t)rows[k] * H4;
        sreg[k]  = ss[k];
    }

#pragma unroll
    for (int it = 0; it < 4; ++it) {          // H4 / 256
        const int c = tid + it * 256;
        vf4 acc = (vf4)0.0f;
#pragma unroll
        for (int k = 0; k < K_EXP; ++k) {
            const vf4 v = __builtin_nontemporal_load(&ex4[rbase[k] + c]);
            acc += v * sreg[k];
        }
        __builtin_nontemporal_store(acc, &o0[c]);
        __builtin_nontemporal_store(acc, &o1[c]);
    }
}

// ---------------------------------------------------------------------------
// Inputs (setup_inputs order):
//   d_in[0] x              (B,H)  f32   -- unused (golden override)
//   d_in[1] expert_ids     (B,K)  i32
//   d_in[2] expert_scales  (B,K)  f32
//   d_in[3] golden_expand_x(B*K,H)f32
//   d_in[4] moe_expert_num scalar i32   -- fixed 64
// Output: (out, out) concatenated -> 2*B*H f32.
// ---------------------------------------------------------------------------
extern "C" void kernel_launch(void* const* d_in, const int* in_sizes, int n_in,
                              void* d_out, int out_size, void* d_ws, size_t ws_size,
                              hipStream_t stream) {
    (void)d_ws; (void)ws_size;
    const int*   eids   = (const int*)d_in[1];
    const float* scales = (const float*)d_in[2];
    const float* ex     = (const float*)d_in[3];
    float* out0 = (float*)d_out;
    float* out1 = (float*)d_out + (size_t)B_TOK * H_DIM;

    moe_fused<<<B_TOK, 256, 0, stream>>>(eids, scales, ex, out0, out1);
}